// Round 3
// baseline (760.273 us; speedup 1.0000x reference)
//
#include <hip/hip_runtime.h>
#include <math.h>

#define VOL (256 * 256 * 256)
#define NSHELL 222
#define SBINS 224
#define NSPLIT 16
#define PI_D 3.14159265358979323846
#define VSTRIDE ((size_t)129 << 16)   // one half-volume: 129 planes of 256x256 float2

// one-time twiddle table: gtw[k] = exp(-2*pi*i*k/256), f64-accurate
__global__ void tw_init(float2* __restrict__ gtw) {
  int t = threadIdx.x;
  double a = -2.0 * PI_D * (double)t / 256.0;
  gtw[t] = make_float2((float)cos(a), (float)sin(a));
}

// LDS-only barrier: orders DS ops across waves WITHOUT draining vmcnt,
// so prefetched global loads / in-flight stores survive the fence.
__device__ __forceinline__ void lds_barrier() {
  asm volatile("s_waitcnt lgkmcnt(0)" ::: "memory");
  __builtin_amdgcn_s_barrier();
}

// wave-level segmented reduce + flush: bins nondecreasing across lanes.
__device__ __forceinline__ void seg_flush(float* sh, int sb, float nv, float pv,
                                          float qv, int l) {
#pragma unroll
  for (int d = 1; d < 64; d <<= 1) {
    int sbo = __shfl_down(sb, d);
    float no = __shfl_down(nv, d);
    float po = __shfl_down(pv, d);
    float qo = __shfl_down(qv, d);
    if (l + d < 64 && sbo == sb) { nv += no; pv += po; qv += qo; }
  }
  int sbp = __shfl_up(sb, 1);
  if (l == 0 || sbp != sb) {
    atomicAdd(&sh[3 * sb + 0], nv);
    atomicAdd(&sh[3 * sb + 1], pv);
    atomicAdd(&sh[3 * sb + 2], qv);
  }
}

__device__ __forceinline__ float2 cmul(float2 a, float2 b) {
  return make_float2(a.x * b.x - a.y * b.y, a.x * b.y + a.y * b.x);
}

// in-register 16-point DFT, natural-order in and out.
__device__ __forceinline__ void fft16(float2* v) {
  const float C1 = 0.92387953251128674f;   // cos(pi/8)
  const float S1 = 0.38268343236508978f;   // sin(pi/8)
  const float R2 = 0.70710678118654752f;   // sqrt(2)/2
  float2 s[16];
#pragma unroll
  for (int p = 0; p < 4; ++p) {
    float2 a = v[p], b = v[p + 4], cc = v[p + 8], d = v[p + 12];
    float2 t0 = make_float2(a.x + cc.x, a.y + cc.y);
    float2 t2 = make_float2(a.x - cc.x, a.y - cc.y);
    float2 t1 = make_float2(b.x + d.x, b.y + d.y);
    float2 t3 = make_float2(b.x - d.x, b.y - d.y);
    s[p]      = make_float2(t0.x + t1.x, t0.y + t1.y);
    s[p + 4]  = make_float2(t2.x + t3.y, t2.y - t3.x);
    s[p + 8]  = make_float2(t0.x - t1.x, t0.y - t1.y);
    s[p + 12] = make_float2(t2.x - t3.y, t2.y + t3.x);
  }
  s[5]  = cmul(s[5],  make_float2(C1, -S1));
  s[6]  = cmul(s[6],  make_float2(R2, -R2));
  s[7]  = cmul(s[7],  make_float2(S1, -C1));
  s[9]  = cmul(s[9],  make_float2(R2, -R2));
  s[10] = cmul(s[10], make_float2(0.f, -1.f));
  s[11] = cmul(s[11], make_float2(-R2, -R2));
  s[13] = cmul(s[13], make_float2(S1, -C1));
  s[14] = cmul(s[14], make_float2(-R2, -R2));
  s[15] = cmul(s[15], make_float2(-C1, S1));
#pragma unroll
  for (int r = 0; r < 4; ++r) {
    float2 u0 = s[4 * r], u1 = s[4 * r + 1], u2 = s[4 * r + 2], u3 = s[4 * r + 3];
    float2 e0 = make_float2(u0.x + u2.x, u0.y + u2.y);
    float2 e1 = make_float2(u0.x - u2.x, u0.y - u2.y);
    float2 o0 = make_float2(u1.x + u3.x, u1.y + u3.y);
    float2 o1 = make_float2(u1.x - u3.x, u1.y - u3.y);
    v[r]      = make_float2(e0.x + o0.x, e0.y + o0.y);
    v[4 + r]  = make_float2(e1.x + o1.y, e1.y - o1.x);
    v[8 + r]  = make_float2(e0.x - o0.x, e0.y - o0.y);
    v[12 + r] = make_float2(e1.x - o1.y, e1.y + o1.x);
  }
}

// ---- Pass 1: pack Z = X + iY, register four-step FFT along z, Hermitian unpack ----
// Persistent blocks, register prefetch of the next tile, lgkm-only barriers.
__global__ __launch_bounds__(256, 4) void fft_z_pack(const float* __restrict__ X,
                                                     const float* __restrict__ Y,
                                                     float2* __restrict__ Gx,
                                                     float2* __restrict__ Gy,
                                                     const float2* __restrict__ gtw) {
  __shared__ float2 zs[256 * 17];    // 34816 B
  __shared__ float2 tws[256];
  int t = threadIdx.x;
  int li = t >> 4, c = t & 15;
  tws[t] = gtw[t];
  const int NT = 4096, Gs = 1024;
  int bid = blockIdx.x;
  float2 pf[16];

#define P1_LOAD(tile)                                                         \
  do {                                                                        \
    int yy = (tile) >> 4, xx = ((((tile) & 15) << 4) + li);                   \
    const float* xb = X + ((size_t)xx << 16) + (yy << 8) + c;                 \
    const float* yb = Y + ((size_t)xx << 16) + (yy << 8) + c;                 \
    _Pragma("unroll") for (int m = 0; m < 16; ++m)                            \
        pf[m] = make_float2(xb[m << 4], yb[m << 4]);                          \
  } while (0)

  P1_LOAD(bid);
  lds_barrier();                      // tws visible
  for (int tile = bid; tile < NT; tile += Gs) {
    float2 v[16];
#pragma unroll
    for (int m = 0; m < 16; ++m) v[m] = pf[m];
    if (tile + Gs < NT) P1_LOAD(tile + Gs);      // prefetch flies under compute
    fft16(v);
#pragma unroll
    for (int k1 = 1; k1 < 16; ++k1) v[k1] = cmul(v[k1], tws[c * k1]);
    // wave-internal 16x16 transpose (rotated slots keep the bank floor)
#pragma unroll
    for (int k1 = 0; k1 < 16; ++k1) zs[(16 * c + ((k1 + c) & 15)) * 17 + li] = v[k1];
    float2 u[16];
#pragma unroll
    for (int j2 = 0; j2 < 16; ++j2) u[j2] = zs[(16 * j2 + ((c + j2) & 15)) * 17 + li];
    fft16(u);                          // u[k2] = Z[16*k2 + c], natural order
    // re-stage full spectrum in natural kz order (own column li)
#pragma unroll
    for (int k2 = 0; k2 < 16; ++k2) zs[(16 * k2 + c) * 17 + li] = u[k2];
    lds_barrier();                     // stage visible to all waves
    // Hermitian unpack; lanes vary x (=c) for coalesced global writes
    {
      int yy = tile >> 4, x0 = ((tile) & 15) << 4;
      float2* gx = Gx + (yy << 8) + (x0 + c);
      float2* gy = Gy + (yy << 8) + (x0 + c);
#pragma unroll
      for (int g = 0; g < 9; ++g) {
        int kz = 16 * g + li;
        if (kz <= 128) {
          float2 a = zs[kz * 17 + c];
          float2 b = zs[((256 - kz) & 255) * 17 + c];
          size_t off = (size_t)kz << 16;
          gx[off] = make_float2(0.5f * (a.x + b.x), 0.5f * (a.y - b.y));
          gy[off] = make_float2(0.5f * (a.y + b.y), 0.5f * (b.x - a.x));
        }
      }
    }
    lds_barrier();                     // unpack reads done before next transpose
  }
#undef P1_LOAD
}

// ---- Pass 2: y-FFT, four-step 16x16 register FFT, persistent + prefetch ----
// tile = vol*2064 + kz*16 + tx
__global__ __launch_bounds__(256, 4) void fft_y(float2* __restrict__ G,
                                                const float2* __restrict__ gtw) {
  __shared__ float2 scr[16 * 273];   // per-column 273-f2 stride kills bank conflicts
  __shared__ float2 tws[256];
  int t = threadIdx.x;
  int xi = t & 15, h = t >> 4;
  tws[t] = gtw[t];
  const int NT = 2 * 129 * 16, Gs = 1024;
  int bid = blockIdx.x;
  float2 pf[16];

#define P2_PTR(tile)                                                          \
  (G + (size_t)((tile) >= 2064) * VSTRIDE +                                   \
   ((size_t)((((tile) >= 2064) ? (tile) - 2064 : (tile)) >> 4) << 16) +       \
   (size_t)((((tile) & 15) << 4) + xi))
#define P2_LOAD(tile)                                                         \
  do {                                                                        \
    float2* Gp_ = P2_PTR(tile);                                               \
    _Pragma("unroll") for (int m = 0; m < 16; ++m)                            \
        pf[m] = Gp_[(size_t)((m << 4) | h) << 8];                             \
  } while (0)

  P2_LOAD(bid);
  lds_barrier();                      // tws visible
  for (int tile = bid; tile < NT; tile += Gs) {
    float2 v[16];
#pragma unroll
    for (int m = 0; m < 16; ++m) v[m] = pf[m];
    if (tile + Gs < NT) P2_LOAD(tile + Gs);
    fft16(v);
#pragma unroll
    for (int k1 = 1; k1 < 16; ++k1) v[k1] = cmul(v[k1], tws[h * k1]);
    lds_barrier();                     // previous tile's scr reads done
    int wb = xi * 273 + h * 17;
#pragma unroll
    for (int k1 = 0; k1 < 16; ++k1) scr[wb + k1] = v[k1];
    lds_barrier();                     // scr visible (h spans waves)
    float2 u[16];
    int rb = xi * 273 + h;
#pragma unroll
    for (int j2 = 0; j2 < 16; ++j2) u[j2] = scr[rb + j2 * 17];
    fft16(u);                          // u[k2] = X[16*k2 + h], natural ky
    float2* Gp = P2_PTR(tile);
#pragma unroll
    for (int k2 = 0; k2 < 16; ++k2) Gp[(size_t)((k2 << 4) | h) << 8] = u[k2];
  }
#undef P2_LOAD
#undef P2_PTR
}

// ---- Pass 3: x-FFT (register four-step) + paired products + segmented reduce ----
// tile = kz*32 + rt (rt: 8-row group). Persistent + prefetch; per-tile sh flush.
__global__ __launch_bounds__(256, 4) void fft_x_reduce(const float2* __restrict__ G,
                                                       double* __restrict__ sums,
                                                       const float2* __restrict__ gtw) {
  // pool roles (fenced): exchange scratch 16x280 f2, then Ax/Ay arrays.
  __shared__ float2 pool[4672];
  __shared__ float sh[3 * SBINS];
  int t = threadIdx.x;
  for (int i = t; i < 3 * SBINS; i += 256) sh[i] = 0.f;
  int vol = t >> 7, tt = t & 127;
  int g = tt >> 4, c = tt & 15;
  const int NT = 129 * 32, Gs = 1024;
  int bid = blockIdx.x;
  float2 pf[16];

#define P3_PTR(tile)                                                          \
  (G + (size_t)vol * VSTRIDE + ((size_t)((tile) >> 5) << 16) +                \
   ((size_t)((((tile) & 31) << 3) + g) << 8))
#define P3_LOAD(tile)                                                         \
  do {                                                                        \
    const float2* Gp_ = P3_PTR(tile);                                         \
    _Pragma("unroll") for (int m = 0; m < 16; ++m) pf[m] = Gp_[(m << 4) | c]; \
  } while (0)

  P3_LOAD(bid);
  for (int tile = bid; tile < NT; tile += Gs) {
    float2 v[16];
#pragma unroll
    for (int m = 0; m < 16; ++m) v[m] = pf[m];
    if (tile + Gs < NT) P3_LOAD(tile + Gs);
    fft16(v);
#pragma unroll
    for (int k1 = 1; k1 < 16; ++k1) v[k1] = cmul(v[k1], gtw[c * k1]);
    lds_barrier();                     // sh init / previous product reads done
    float2 u[16];
    {
      int sbase = ((vol << 3) | g) * 280;    // 16-lane wave-internal exchange
#pragma unroll
      for (int k1 = 0; k1 < 16; ++k1) pool[sbase + c * 17 + k1] = v[k1];
#pragma unroll
      for (int j2 = 0; j2 < 16; ++j2) u[j2] = pool[sbase + j2 * 17 + c];
      fft16(u);                              // u[k2] = X[16*k2 + c]
    }
    lds_barrier();                     // scratch reads done before A overwrite
    {
      float2* A = pool + vol * 2336;
#pragma unroll
      for (int k2 = 0; k2 < 16; ++k2) {
        int kx = (k2 << 4) | c;
        A[kx * 9 + k2 + g] = u[k2];          // addr = kx*9 + (kx>>4) + g
      }
    }
    lds_barrier();                     // A visible to all waves
    int kz = tile >> 5, rt = tile & 31;
    int fz = kz - ((kz & 128) ? 256 : 0);
    int fz2 = fz * fz;
    int w = t >> 6, l = t & 63;
    const float2* Ax = pool;
    const float2* Ay = pool + 2336;
#pragma unroll
    for (int rr = 0; rr < 2; ++rr) {
      int row = (w << 1) | rr;               // local row 0..7
      int ky = (rt << 3) + row;              // natural ky
      int fy = ky - ((ky & 128) ? 256 : 0);
      int c2 = fy * fy + fz2;
#pragma unroll
      for (int pass = 0; pass < 2; ++pass) {
        int kx = (pass << 6) | l;
        float2 xv = Ax[kx * 9 + (kx >> 4) + row];
        float2 yv = Ay[kx * 9 + (kx >> 4) + row];
        float nv = xv.x * yv.x + xv.y * yv.y;
        float pv = xv.x * xv.x + xv.y * xv.y;
        float qv = yv.x * yv.x + yv.y * yv.y;
        if (kx != 0) {
          int mk = 256 - kx;
          float2 mx = Ax[mk * 9 + (mk >> 4) + row];
          float2 my = Ay[mk * 9 + (mk >> 4) + row];
          nv += mx.x * my.x + mx.y * my.y;
          pv += mx.x * mx.x + mx.y * mx.y;
          qv += my.x * my.x + my.y * my.y;
        }
        int m = kx * kx + c2;
        int sb = (int)sqrtf((float)m);
        while (sb * sb > m) --sb;
        while ((sb + 1) * (sb + 1) <= m) ++sb;
        seg_flush(sh, sb, nv, pv, qv, l);
      }
      if (l == 0) {                          // kx = 128 (self-mirrored)
        float2 xv = Ax[128 * 9 + 8 + row];
        float2 yv = Ay[128 * 9 + 8 + row];
        int m = 16384 + c2;
        int sb = (int)sqrtf((float)m);
        while (sb * sb > m) --sb;
        while ((sb + 1) * (sb + 1) <= m) ++sb;
        atomicAdd(&sh[3 * sb + 0], xv.x * yv.x + xv.y * yv.y);
        atomicAdd(&sh[3 * sb + 1], xv.x * xv.x + xv.y * xv.y);
        atomicAdd(&sh[3 * sb + 2], yv.x * yv.x + yv.y * yv.y);
      }
    }
    lds_barrier();                     // all sh atomics visible
    float wf = (kz == 0 || kz == 128) ? 1.f : 2.f;   // kz-plane Hermitian weight
    double* sp = sums + (size_t)(tile & (NSPLIT - 1)) * (3 * SBINS);
    for (int i = t; i < 3 * SBINS; i += 256) {
      float vv = sh[i];
      if (vv != 0.f) atomicAdd(&sp[i], (double)(wf * vv));
      sh[i] = 0.f;                     // rezero for next tile (ordered by top fence)
    }
  }
#undef P3_LOAD
#undef P3_PTR
}

__global__ void finalize(const double* __restrict__ sums, float* __restrict__ out) {
  __shared__ double red[2 * 3 * SBINS];
  int t = threadIdx.x;
  for (int i = t; i < 2 * 3 * SBINS; i += 256) {
    int b = i / (3 * SBINS), k = i - b * (3 * SBINS);
    const double* s = sums + (size_t)b * NSPLIT * 3 * SBINS + k;
    double a = 0.0;
#pragma unroll
    for (int sp = 0; sp < NSPLIT; ++sp) a += s[(size_t)sp * 3 * SBINS];
    red[i] = a;
  }
  __syncthreads();
  if (t == 0) {
    double acc = 0.0;
    for (int b = 0; b < 2; ++b) {
      const double* s = red + b * 3 * SBINS;
      for (int k = 0; k < NSHELL; ++k)
        acc += s[3 * k] / sqrt(s[3 * k + 1] * s[3 * k + 2] + 1e-8);
    }
    out[0] = (float)(acc / (2.0 * (double)NSHELL));
  }
}

extern "C" void kernel_launch(void* const* d_in, const int* in_sizes, int n_in,
                              void* d_out, int out_size, void* d_ws, size_t ws_size,
                              hipStream_t stream) {
  const float* X = (const float*)d_in[0];
  const float* Y = (const float*)d_in[1];
  float2* Gx = (float2*)d_ws;                 // 129 planes
  float2* Gy = Gx + VSTRIDE;                  // 129 planes
  double* sums = (double*)((char*)d_ws + (size_t)2 * VSTRIDE * sizeof(float2));
  float2* gtw = (float2*)(sums + (size_t)2 * NSPLIT * 3 * SBINS);

  hipMemsetAsync(sums, 0, (size_t)2 * NSPLIT * 3 * SBINS * sizeof(double), stream);
  tw_init<<<1, 256, 0, stream>>>(gtw);

  for (int b = 0; b < 2; ++b) {
    fft_z_pack<<<1024, 256, 0, stream>>>(X + (size_t)b * VOL, Y + (size_t)b * VOL, Gx, Gy, gtw);
    fft_y<<<1024, 256, 0, stream>>>(Gx, gtw);
    fft_x_reduce<<<1024, 256, 0, stream>>>(Gx, sums + (size_t)b * NSPLIT * 3 * SBINS, gtw);
  }
  finalize<<<1, 256, 0, stream>>>(sums, (float*)d_out);
}

// Round 4
// 671.467 us; speedup vs baseline: 1.1323x; 1.1323x over previous
//
#include <hip/hip_runtime.h>
#include <math.h>

#define VOL (256 * 256 * 256)
#define NSHELL 222
#define SBINS 224
#define NSPLIT 16
#define PI_D 3.14159265358979323846
#define VSTRIDE ((size_t)129 << 16)   // one half-volume: 129 planes of 256x256 float2

// one-time twiddle table: gtw[k] = exp(-2*pi*i*k/256), f64-accurate
__global__ void tw_init(float2* __restrict__ gtw) {
  int t = threadIdx.x;
  double a = -2.0 * PI_D * (double)t / 256.0;
  gtw[t] = make_float2((float)cos(a), (float)sin(a));
}

// wave-level segmented reduce + flush: bins nondecreasing across lanes.
__device__ __forceinline__ void seg_flush(float* sh, int sb, float nv, float pv,
                                          float qv, int l) {
#pragma unroll
  for (int d = 1; d < 64; d <<= 1) {
    int sbo = __shfl_down(sb, d);
    float no = __shfl_down(nv, d);
    float po = __shfl_down(pv, d);
    float qo = __shfl_down(qv, d);
    if (l + d < 64 && sbo == sb) { nv += no; pv += po; qv += qo; }
  }
  int sbp = __shfl_up(sb, 1);
  if (l == 0 || sbp != sb) {
    atomicAdd(&sh[3 * sb + 0], nv);
    atomicAdd(&sh[3 * sb + 1], pv);
    atomicAdd(&sh[3 * sb + 2], qv);
  }
}

__device__ __forceinline__ float2 cmul(float2 a, float2 b) {
  return make_float2(a.x * b.x - a.y * b.y, a.x * b.y + a.y * b.x);
}

// in-register 16-point DFT, natural-order in and out.
__device__ __forceinline__ void fft16(float2* v) {
  const float C1 = 0.92387953251128674f;   // cos(pi/8)
  const float S1 = 0.38268343236508978f;   // sin(pi/8)
  const float R2 = 0.70710678118654752f;   // sqrt(2)/2
  float2 s[16];
#pragma unroll
  for (int p = 0; p < 4; ++p) {
    float2 a = v[p], b = v[p + 4], cc = v[p + 8], d = v[p + 12];
    float2 t0 = make_float2(a.x + cc.x, a.y + cc.y);
    float2 t2 = make_float2(a.x - cc.x, a.y - cc.y);
    float2 t1 = make_float2(b.x + d.x, b.y + d.y);
    float2 t3 = make_float2(b.x - d.x, b.y - d.y);
    s[p]      = make_float2(t0.x + t1.x, t0.y + t1.y);
    s[p + 4]  = make_float2(t2.x + t3.y, t2.y - t3.x);
    s[p + 8]  = make_float2(t0.x - t1.x, t0.y - t1.y);
    s[p + 12] = make_float2(t2.x - t3.y, t2.y + t3.x);
  }
  s[5]  = cmul(s[5],  make_float2(C1, -S1));
  s[6]  = cmul(s[6],  make_float2(R2, -R2));
  s[7]  = cmul(s[7],  make_float2(S1, -C1));
  s[9]  = cmul(s[9],  make_float2(R2, -R2));
  s[10] = cmul(s[10], make_float2(0.f, -1.f));
  s[11] = cmul(s[11], make_float2(-R2, -R2));
  s[13] = cmul(s[13], make_float2(S1, -C1));
  s[14] = cmul(s[14], make_float2(-R2, -R2));
  s[15] = cmul(s[15], make_float2(-C1, S1));
#pragma unroll
  for (int r = 0; r < 4; ++r) {
    float2 u0 = s[4 * r], u1 = s[4 * r + 1], u2 = s[4 * r + 2], u3 = s[4 * r + 3];
    float2 e0 = make_float2(u0.x + u2.x, u0.y + u2.y);
    float2 e1 = make_float2(u0.x - u2.x, u0.y - u2.y);
    float2 o0 = make_float2(u1.x + u3.x, u1.y + u3.y);
    float2 o1 = make_float2(u1.x - u3.x, u1.y - u3.y);
    v[r]      = make_float2(e0.x + o0.x, e0.y + o0.y);
    v[4 + r]  = make_float2(e1.x + o1.y, e1.y - o1.x);
    v[8 + r]  = make_float2(e0.x - o0.x, e0.y - o0.y);
    v[12 + r] = make_float2(e1.x - o1.y, e1.y + o1.x);
  }
}

// ---- Pass 1: pack Z = X + iY, register four-step FFT along z, Hermitian unpack ----
// 128-thread blocks, 8 x-lines each; LDS 20480 B -> 8 blocks/CU for latency overlap.
// 16-lane group per line (li = t>>4, c = t&15): all FFT exchanges are wave-internal.
__global__ __launch_bounds__(128, 4) void fft_z_pack(const float* __restrict__ X,
                                                     const float* __restrict__ Y,
                                                     float2* __restrict__ Gx,
                                                     float2* __restrict__ Gy,
                                                     const float2* __restrict__ gtw) {
  __shared__ float2 zs[256 * 9];     // 18432 B, [z*9 + li]
  __shared__ float2 tws[256];        // 2048 B
  int t = threadIdx.x;
  int li = t >> 4, c = t & 15;
  tws[t] = gtw[t];
  tws[t + 128] = gtw[t + 128];
  int y = blockIdx.x >> 5;
  int x0 = (blockIdx.x & 31) << 3;
  const float4* xp = (const float4*)(X + (((size_t)(x0 + li)) << 16) + ((size_t)y << 8));
  const float4* yp = (const float4*)(Y + (((size_t)(x0 + li)) << 16) + ((size_t)y << 8));
  // Phase A: coalesced float4 load, stage Z = X + iY (group owns line li)
#pragma unroll
  for (int it = 0; it < 4; ++it) {
    float4 a = xp[c + 16 * it];
    float4 b = yp[c + 16 * it];
    int z0 = 4 * c + 64 * it;
    zs[(z0 + 0) * 9 + li] = make_float2(a.x, b.x);
    zs[(z0 + 1) * 9 + li] = make_float2(a.y, b.y);
    zs[(z0 + 2) * 9 + li] = make_float2(a.z, b.z);
    zs[(z0 + 3) * 9 + li] = make_float2(a.w, b.w);
  }
  __syncthreads();                    // tws visible (zs is wave-local anyway)
  // Phase B: v[j1] = z[16*j1 + c], FFT over j1 -> k1, twiddle W256^(c*k1)
  float2 v[16];
#pragma unroll
  for (int m = 0; m < 16; ++m) v[m] = zs[(16 * m + c) * 9 + li];
  fft16(v);
#pragma unroll
  for (int k1 = 1; k1 < 16; ++k1) v[k1] = cmul(v[k1], tws[c * k1]);
  // Phase C: wave-internal 16x16 transpose (rotated slots spread banks)
#pragma unroll
  for (int k1 = 0; k1 < 16; ++k1) zs[(16 * c + ((k1 + c) & 15)) * 9 + li] = v[k1];
  float2 u[16];
#pragma unroll
  for (int j2 = 0; j2 < 16; ++j2) u[j2] = zs[(16 * j2 + ((c + j2) & 15)) * 9 + li];
  fft16(u);                           // u[k2] = Z[16*k2 + c], natural order
  // Phase D: re-stage full spectrum in natural kz order
#pragma unroll
  for (int k2 = 0; k2 < 16; ++k2) zs[(16 * k2 + c) * 9 + li] = u[k2];
  __syncthreads();                    // unpack crosses waves
  // Phase E: Hermitian unpack; lanes vary x for coalesced 64B global writes
  int xo = t & 7, ko = t >> 3;        // x-line 0..7, kz row 0..15
  float2* gx = Gx + ((size_t)y << 8) + (size_t)(x0 + xo);
  float2* gy = Gy + ((size_t)y << 8) + (size_t)(x0 + xo);
#pragma unroll
  for (int g = 0; g < 9; ++g) {
    int kz = 16 * g + ko;
    if (kz <= 128) {
      float2 a = zs[kz * 9 + xo];
      float2 b = zs[((256 - kz) & 255) * 9 + xo];
      size_t off = (size_t)kz << 16;
      gx[off] = make_float2(0.5f * (a.x + b.x), 0.5f * (a.y - b.y));
      gy[off] = make_float2(0.5f * (a.y + b.y), 0.5f * (b.x - a.x));
    }
  }
}

// ---- Pass 2: y-FFT, four-step 16x16 register FFT; natural ky order ----
// 128-thread blocks, 8 x-columns; LDS 19520 B -> 8 blocks/CU.
__global__ __launch_bounds__(128, 4) void fft_y(float2* __restrict__ G,
                                                const float2* __restrict__ gtw) {
  __shared__ float2 scr[8 * 273];    // per-column 273-f2 stride
  __shared__ float2 tws[256];
  int t = threadIdx.x;
  int xi = t & 7, h = t >> 3;        // xi: column 0..7, h: j mod 16 (then k1)
  tws[t] = gtw[t];
  tws[t + 128] = gtw[t + 128];
  int x0 = blockIdx.x << 3;
  int kz = blockIdx.y;
  float2* Gp = G + (size_t)blockIdx.z * VSTRIDE + ((size_t)kz << 16) + (size_t)(x0 + xi);
  __syncthreads();                   // tws visible
  float2 v[16];
#pragma unroll
  for (int m = 0; m < 16; ++m) v[m] = Gp[(size_t)((m << 4) | h) << 8];
  fft16(v);                          // v[k1] = Y_h[k1]
#pragma unroll
  for (int k1 = 1; k1 < 16; ++k1) v[k1] = cmul(v[k1], tws[h * k1]);
  int wb = xi * 273 + h * 17;
#pragma unroll
  for (int k1 = 0; k1 < 16; ++k1) scr[wb + k1] = v[k1];
  __syncthreads();                   // h spans waves -> block barrier
  float2 u[16];
  int rb = xi * 273 + h;
#pragma unroll
  for (int j2 = 0; j2 < 16; ++j2) u[j2] = scr[rb + j2 * 17];
  fft16(u);                          // u[k2] = X[16*k2 + h], natural ky
#pragma unroll
  for (int k2 = 0; k2 < 16; ++k2) Gp[(size_t)((k2 << 4) | h) << 8] = u[k2];
}

// ---- Pass 3: x-FFT (register four-step) + paired products + segmented reduce ----
__global__ __launch_bounds__(256, 4) void fft_x_reduce(const float2* __restrict__ G,
                                                       double* __restrict__ sums,
                                                       const float2* __restrict__ gtw) {
  // pool serves two roles separated by a barrier:
  //  - exchange scratch: 16 contexts (vol,g) * 280 f2, wave-internal (no barrier)
  //  - A arrays: Ax = pool[0..2335], Ay = pool[2336..4671], addr = kx*9 + (kx>>4) + g
  __shared__ float2 pool[4672];
  __shared__ float sh[3 * SBINS];
  int t = threadIdx.x;
  for (int i = t; i < 3 * SBINS; i += 256) sh[i] = 0.f;
  int vol = t >> 7, tt = t & 127;
  int g = tt >> 4, c = tt & 15;      // g: row in tile (0..7), c: j mod 16 (then k1)
  int kz = blockIdx.y;
  int r0 = blockIdx.x << 3;
  const float2* Gp = G + (size_t)vol * VSTRIDE + ((size_t)kz << 16) + ((size_t)(r0 + g) << 8);
  float2 v[16];
#pragma unroll
  for (int m = 0; m < 16; ++m) v[m] = Gp[(m << 4) | c];
  fft16(v);
#pragma unroll
  for (int k1 = 1; k1 < 16; ++k1) v[k1] = cmul(v[k1], gtw[c * k1]);
  {
    int sbase = ((vol << 3) | g) * 280;      // 16-lane context: wave-internal exchange
#pragma unroll
    for (int k1 = 0; k1 < 16; ++k1) pool[sbase + c * 17 + k1] = v[k1];
    float2 u[16];
#pragma unroll
    for (int j2 = 0; j2 < 16; ++j2) u[j2] = pool[sbase + j2 * 17 + c];
    fft16(u);                                // u[k2] = X[16*k2 + c]
    __syncthreads();                         // scratch -> A repurposing fence (covers sh init)
    float2* A = pool + vol * 2336;
#pragma unroll
    for (int k2 = 0; k2 < 16; ++k2) {
      int kx = (k2 << 4) | c;
      A[kx * 9 + k2 + g] = u[k2];            // apos(kx,g); kx>>4 == k2
    }
  }
  __syncthreads();
  int fz = kz - ((kz & 128) ? 256 : 0);
  int fz2 = fz * fz;
  int w = t >> 6, l = t & 63;
  const float2* Ax = pool;
  const float2* Ay = pool + 2336;
#pragma unroll
  for (int rr = 0; rr < 2; ++rr) {
    int row = (w << 1) | rr;                 // local row 0..7
    int ky = r0 + row;                       // natural ky
    int fy = ky - ((ky & 128) ? 256 : 0);
    int c2 = fy * fy + fz2;
#pragma unroll
    for (int pass = 0; pass < 2; ++pass) {
      int kx = (pass << 6) | l;
      float2 xv = Ax[kx * 9 + (kx >> 4) + row];
      float2 yv = Ay[kx * 9 + (kx >> 4) + row];
      float nv = xv.x * yv.x + xv.y * yv.y;
      float pv = xv.x * xv.x + xv.y * xv.y;
      float qv = yv.x * yv.x + yv.y * yv.y;
      if (kx != 0) {
        int mk = 256 - kx;
        float2 mx = Ax[mk * 9 + (mk >> 4) + row];
        float2 my = Ay[mk * 9 + (mk >> 4) + row];
        nv += mx.x * my.x + mx.y * my.y;
        pv += mx.x * mx.x + mx.y * mx.y;
        qv += my.x * my.x + my.y * my.y;
      }
      int m = kx * kx + c2;
      int sb = (int)sqrtf((float)m);
      while (sb * sb > m) --sb;
      while ((sb + 1) * (sb + 1) <= m) ++sb;
      seg_flush(sh, sb, nv, pv, qv, l);
    }
    if (l == 0) {                            // kx = 128 (self-mirrored)
      float2 xv = Ax[128 * 9 + 8 + row];
      float2 yv = Ay[128 * 9 + 8 + row];
      int m = 16384 + c2;
      int sb = (int)sqrtf((float)m);
      while (sb * sb > m) --sb;
      while ((sb + 1) * (sb + 1) <= m) ++sb;
      atomicAdd(&sh[3 * sb + 0], xv.x * yv.x + xv.y * yv.y);
      atomicAdd(&sh[3 * sb + 1], xv.x * xv.x + xv.y * xv.y);
      atomicAdd(&sh[3 * sb + 2], yv.x * yv.x + yv.y * yv.y);
    }
  }
  __syncthreads();
  float wf = (kz == 0 || kz == 128) ? 1.f : 2.f;   // kz-plane Hermitian weight
  double* sp = sums + (size_t)(blockIdx.x & (NSPLIT - 1)) * (3 * SBINS);
  for (int i = t; i < 3 * SBINS; i += 256) {
    float vv = sh[i];
    if (vv != 0.f) atomicAdd(&sp[i], (double)(wf * vv));
  }
}

__global__ void finalize(const double* __restrict__ sums, float* __restrict__ out) {
  __shared__ double red[2 * 3 * SBINS];
  int t = threadIdx.x;
  for (int i = t; i < 2 * 3 * SBINS; i += 256) {
    int b = i / (3 * SBINS), k = i - b * (3 * SBINS);
    const double* s = sums + (size_t)b * NSPLIT * 3 * SBINS + k;
    double a = 0.0;
#pragma unroll
    for (int sp = 0; sp < NSPLIT; ++sp) a += s[(size_t)sp * 3 * SBINS];
    red[i] = a;
  }
  __syncthreads();
  if (t == 0) {
    double acc = 0.0;
    for (int b = 0; b < 2; ++b) {
      const double* s = red + b * 3 * SBINS;
      for (int k = 0; k < NSHELL; ++k)
        acc += s[3 * k] / sqrt(s[3 * k + 1] * s[3 * k + 2] + 1e-8);
    }
    out[0] = (float)(acc / (2.0 * (double)NSHELL));
  }
}

extern "C" void kernel_launch(void* const* d_in, const int* in_sizes, int n_in,
                              void* d_out, int out_size, void* d_ws, size_t ws_size,
                              hipStream_t stream) {
  const float* X = (const float*)d_in[0];
  const float* Y = (const float*)d_in[1];
  float2* Gx = (float2*)d_ws;                 // 129 planes
  float2* Gy = Gx + VSTRIDE;                  // 129 planes
  double* sums = (double*)((char*)d_ws + (size_t)2 * VSTRIDE * sizeof(float2));
  float2* gtw = (float2*)(sums + (size_t)2 * NSPLIT * 3 * SBINS);

  hipMemsetAsync(sums, 0, (size_t)2 * NSPLIT * 3 * SBINS * sizeof(double), stream);
  tw_init<<<1, 256, 0, stream>>>(gtw);

  for (int b = 0; b < 2; ++b) {
    fft_z_pack<<<8192, 128, 0, stream>>>(X + (size_t)b * VOL, Y + (size_t)b * VOL, Gx, Gy, gtw);
    fft_y<<<dim3(32, 129, 2), 128, 0, stream>>>(Gx, gtw);
    fft_x_reduce<<<dim3(32, 129), 256, 0, stream>>>(Gx, sums + (size_t)b * NSPLIT * 3 * SBINS, gtw);
  }
  finalize<<<1, 256, 0, stream>>>(sums, (float*)d_out);
}